// Round 10
// baseline (114.975 us; speedup 1.0000x reference)
//
#include <hip/hip_runtime.h>
#include <hip/hip_bf16.h>

// AgentModel: B=8, N=256, TD=128, LH=128, H=128, A=5, L=2
constexpr int Nc = 256;
constexpr int Hc = 128;
constexpr int Ac = 5;
constexpr int Mc = 2048;

__device__ __forceinline__ unsigned long long aload8(const void* p) {
  return __hip_atomic_load((const unsigned long long*)p, __ATOMIC_RELAXED,
                           __HIP_MEMORY_SCOPE_AGENT);
}
__device__ __forceinline__ void astore(float* p, float v) {
  __hip_atomic_store(p, v, __ATOMIC_RELAXED, __HIP_MEMORY_SCOPE_AGENT);
}

struct P {
  const float *theta, *cell, *encW, *encb, *msgW, *msgb, *updW, *updb;
  const float *hW1, *hb1, *hW2, *hb2;
  float *out, *pj0, *pj1;
  int* ctr;  // [2][8 batches x 64-stride], zeroed per launch
};

// One kernel. Block blk: batch b=blk&7, row-slice s=blk>>3 (8 rows).
// Cross-block data = pj only, via agent-scope (MALL-coherent) ops; weights
// stay L2-cached. Per-batch 32-block atomic barrier, no grid.sync.
__global__ __launch_bounds__(512) void fused(P p) {
  __shared__ float stage[16384];  // 64 KB: enc-x staging / pj chunk [128][128]
  __shared__ float hs[1024];      // h (8 rows)
  __shared__ float pis[1024];     // pi (8 rows)
  __shared__ float xs[1024];      // h+agg / z
  const int tid = threadIdx.x;
  const int blk = blockIdx.x;
  const int b = blk & 7;
  const int s = blk >> 3;
  const int m0 = b * 256 + s * 8;  // global row base
  const int o = tid & 127;
  const int rg = tid >> 7;  // 0..3 -> rows rg*2, rg*2+1
  const int r0 = rg * 2;

  // ---- encoder ----
  {
    int idx = tid * 4, r = idx >> 8, d = idx & 255;
    const float* src = (d < 128) ? p.theta + (m0 + r) * 128 + d
                                 : p.cell + (m0 + r) * 128 + (d - 128);
    *reinterpret_cast<float4*>(&stage[idx]) =
        *reinterpret_cast<const float4*>(src);
  }
  __syncthreads();
  {
    float a0 = 0.f, a1 = 0.f;
    const float* wr = p.encW + o * 256;
#pragma unroll 8
    for (int k = 0; k < 256; k += 4) {
      float4 w = *reinterpret_cast<const float4*>(wr + k);
      const float* x0 = &stage[r0 * 256 + k];
      const float* x1 = &stage[(r0 + 1) * 256 + k];
      a0 += w.x * x0[0] + w.y * x0[1] + w.z * x0[2] + w.w * x0[3];
      a1 += w.x * x1[0] + w.y * x1[1] + w.z * x1[2] + w.w * x1[3];
    }
    float bb = p.encb[o];
    hs[r0 * 128 + o] = fmaxf(a0 + bb, 0.f);
    hs[(r0 + 1) * 128 + o] = fmaxf(a1 + bb, 0.f);
  }
  __syncthreads();

  // ---- two message-passing layers ----
  for (int l = 0; l < 2; ++l) {
    float* pjX = l ? p.pj1 : p.pj0;

    {  // pj/pi from hs: 256 cols x 2 rowgroups of 4 rows
      const int c = tid & 255;
      const int rg2 = tid >> 8;  // 0..1
      const int rr0 = rg2 * 4;
      const float* wr = p.msgW + l * 32768 + (c & 127) * 256 + ((c >> 7) << 7);
      float a[4] = {0.f, 0.f, 0.f, 0.f};
#pragma unroll 8
      for (int k = 0; k < 128; k += 4) {
        float4 w = *reinterpret_cast<const float4*>(wr + k);
#pragma unroll
        for (int r = 0; r < 4; ++r) {
          const float* x = &hs[(rr0 + r) * 128 + k];
          a[r] += w.x * x[0] + w.y * x[1] + w.z * x[2] + w.w * x[3];
        }
      }
      if (c < 128) {  // pj -> global, MALL-coherent
#pragma unroll
        for (int r = 0; r < 4; ++r)
          astore(pjX + (m0 + rr0 + r) * 128 + c, a[r]);
      } else {  // pi -> LDS
#pragma unroll
        for (int r = 0; r < 4; ++r) pis[(rr0 + r) * 128 + (c - 128)] = a[r];
      }
    }
    // ---- per-batch barrier: all 32 blocks' pj stores visible ----
    asm volatile("s_waitcnt vmcnt(0)" ::: "memory");
    __syncthreads();
    if (tid == 0) {
      int* c = p.ctr + l * 512 + b * 64;
      __hip_atomic_fetch_add(c, 1, __ATOMIC_RELAXED, __HIP_MEMORY_SCOPE_AGENT);
      while (__hip_atomic_load(c, __ATOMIC_RELAXED,
                               __HIP_MEMORY_SCOPE_AGENT) < 32)
        __builtin_amdgcn_s_sleep(2);
    }
    __syncthreads();

    // ---- agg: stage batch pj in two 64 KB chunks, consume from LDS ----
    const float mbo = p.msgb[l * 128 + o];
    float s0 = pis[r0 * 128 + o] + mbo;
    float s1 = pis[(r0 + 1) * 128 + o] + mbo;
    float vsum = 0.f, ab0 = 0.f, ab1 = 0.f, dj0 = 0.f, dj1 = 0.f;
#pragma unroll
    for (int c = 0; c < 2; ++c) {
      const unsigned long long* src =
          (const unsigned long long*)(pjX + (b * 256 + c * 128) * 128);
      unsigned long long* dst = (unsigned long long*)stage;
#pragma unroll
      for (int i = 0; i < 16; ++i)
        dst[tid + i * 512] = aload8(src + tid + i * 512);
      __syncthreads();
      if ((s >> 4) == c) {  // own rows live in this chunk: capture diag
        int ir = s * 8 - c * 128;
        dj0 = stage[(ir + r0) * 128 + o];
        dj1 = stage[(ir + r0 + 1) * 128 + o];
      }
#pragma unroll 8
      for (int j = 0; j < 128; ++j) {
        float v = stage[j * 128 + o];
        vsum += v;
        ab0 += fabsf(v + s0);
        ab1 += fabsf(v + s1);
      }
      __syncthreads();
    }
    {  // combine: sum_j relu(v+s) = 0.5*(sum v + 256*s + sum|v+s|)
      float d0 = fmaxf(dj0 + s0, 0.f);
      float d1 = fmaxf(dj1 + s1, 0.f);
      xs[r0 * 128 + o] =
          hs[r0 * 128 + o] + (0.5f * (vsum + 256.f * s0 + ab0) - d0) * (1.f / 255.f);
      xs[(r0 + 1) * 128 + o] =
          hs[(r0 + 1) * 128 + o] +
          (0.5f * (vsum + 256.f * s1 + ab1) - d1) * (1.f / 255.f);
    }
    __syncthreads();

    {  // ---- update GEMM: xs -> hs ----
      float a0 = 0.f, a1 = 0.f;
      const float* wr = p.updW + l * 16384 + o * 128;
#pragma unroll 8
      for (int k = 0; k < 128; k += 4) {
        float4 w = *reinterpret_cast<const float4*>(wr + k);
        const float* x0 = &xs[r0 * 128 + k];
        const float* x1 = &xs[(r0 + 1) * 128 + k];
        a0 += w.x * x0[0] + w.y * x0[1] + w.z * x0[2] + w.w * x0[3];
        a1 += w.x * x1[0] + w.y * x1[1] + w.z * x1[2] + w.w * x1[3];
      }
      float bo = p.updb[l * 128 + o];
      hs[r0 * 128 + o] = fmaxf(a0 + bo, 0.f);
      hs[(r0 + 1) * 128 + o] = fmaxf(a1 + bo, 0.f);
    }
    __syncthreads();
  }

  // ---- head ----
  {
    float a0 = 0.f, a1 = 0.f;
    const float* wr = p.hW1 + o * 128;
#pragma unroll 8
    for (int k = 0; k < 128; k += 4) {
      float4 w = *reinterpret_cast<const float4*>(wr + k);
      const float* x0 = &hs[r0 * 128 + k];
      const float* x1 = &hs[(r0 + 1) * 128 + k];
      a0 += w.x * x0[0] + w.y * x0[1] + w.z * x0[2] + w.w * x0[3];
      a1 += w.x * x1[0] + w.y * x1[1] + w.z * x1[2] + w.w * x1[3];
    }
    float bo = p.hb1[o];
    xs[r0 * 128 + o] = fmaxf(a0 + bo, 0.f);
    xs[(r0 + 1) * 128 + o] = fmaxf(a1 + bo, 0.f);
  }
  __syncthreads();
  if (tid < 8 * Ac) {  // 40 dots of length 128
    const int r = tid / Ac;
    const int a = tid % Ac;
    const float* wr2 = p.hW2 + a * 128;
    float sacc = 0.f;
#pragma unroll 8
    for (int k = 0; k < 128; k += 4) {
      float4 w = *reinterpret_cast<const float4*>(wr2 + k);
      const float* z = &xs[r * 128 + k];
      sacc += w.x * z[0] + w.y * z[1] + w.z * z[2] + w.w * z[3];
    }
    p.out[(m0 + r) * Ac + a] = sacc + p.hb2[a];
  }
}

// ---------------------------------------------------------------------------
extern "C" void kernel_launch(void* const* d_in, const int* in_sizes, int n_in,
                              void* d_out, int out_size, void* d_ws, size_t ws_size,
                              hipStream_t stream) {
  float* ws = (float*)d_ws;
  const int MH = Mc * Hc;  // 262144 floats = 1 MB

  P p;
  p.theta = (const float*)d_in[0];
  p.cell  = (const float*)d_in[1];
  p.encW  = (const float*)d_in[2];
  p.encb  = (const float*)d_in[3];
  p.msgW  = (const float*)d_in[4];
  p.msgb  = (const float*)d_in[5];
  p.updW  = (const float*)d_in[6];
  p.updb  = (const float*)d_in[7];
  p.hW1   = (const float*)d_in[8];
  p.hb1   = (const float*)d_in[9];
  p.hW2   = (const float*)d_in[10];
  p.hb2   = (const float*)d_in[11];
  p.out   = (float*)d_out;
  p.pj0   = ws;
  p.pj1   = ws + MH;
  p.ctr   = (int*)(ws + 2 * MH);

  // zero the barrier counters (2 layers x 8 batches x 64-int stride)
  hipMemsetAsync((void*)p.ctr, 0, 2 * 512 * sizeof(int), stream);

  void* args[] = {&p};
  hipLaunchCooperativeKernel((void*)fused, dim3(256), dim3(512), args, 0,
                             stream);
}

// Round 11
// 92.264 us; speedup vs baseline: 1.2462x; 1.2462x over previous
//
#include <hip/hip_runtime.h>
#include <hip/hip_bf16.h>

// AgentModel: B=8, N=256, TD=128, LH=128, H=128, A=5, L=2
constexpr int Nc = 256;
constexpr int Hc = 128;
constexpr int Ac = 5;
constexpr int Mc = 2048;
constexpr int R = 16;         // rows per block
constexpr int GRID = Mc / R;  // 128 blocks, 512 threads each

// ---------------------------------------------------------------------------
// K1: encoder + pj/pi of layer 0.  128 blocks x 512 threads, 16 rows/block.
// ---------------------------------------------------------------------------
__global__ __launch_bounds__(512) void k1_enc_pjpi(
    const float* __restrict__ theta, const float* __restrict__ cell,
    const float* __restrict__ encW, const float* __restrict__ encb,
    const float* __restrict__ msgW0, float* __restrict__ h,
    float* __restrict__ pj, float* __restrict__ pi) {
  __shared__ float xs[R][256];  // 16 KB
  __shared__ float hs[R][Hc];   // 8 KB
  const int m0 = blockIdx.x * R;
  const int tid = threadIdx.x;

  {  // stage x = [theta|cell]: 16x256 floats, 8 consecutive per thread
    int idx = tid * 8, r = idx >> 8, d = idx & 255;
    const float* src = (d < 128) ? theta + (m0 + r) * 128 + d
                                 : cell + (m0 + r) * 128 + (d - 128);
    *reinterpret_cast<float4*>(&xs[r][d]) = *reinterpret_cast<const float4*>(src);
    src = (d + 4 < 128) ? theta + (m0 + r) * 128 + d + 4
                        : cell + (m0 + r) * 128 + (d + 4 - 128);
    *reinterpret_cast<float4*>(&xs[r][d + 4]) =
        *reinterpret_cast<const float4*>(src);
  }
  __syncthreads();

  const int o = tid & 127;
  const int rg = tid >> 7;  // 0..3 -> rows rg*4 .. rg*4+3
  {                         // encoder: 4 rows per thread
    const int r0 = rg * 4;
    float a[4] = {0.f, 0.f, 0.f, 0.f};
    const float* wr = encW + o * 256;
#pragma unroll 8
    for (int k = 0; k < 256; k += 4) {
      float4 w = *reinterpret_cast<const float4*>(wr + k);
#pragma unroll
      for (int r = 0; r < 4; ++r) {
        const float* x = &xs[r0 + r][k];
        a[r] += w.x * x[0] + w.y * x[1] + w.z * x[2] + w.w * x[3];
      }
    }
    const float bb = encb[o];
#pragma unroll
    for (int r = 0; r < 4; ++r) {
      float v = fmaxf(a[r] + bb, 0.f);
      hs[r0 + r][o] = v;
      h[(m0 + r0 + r) * Hc + o] = v;
    }
  }
  __syncthreads();

  {  // pj/pi layer 0: 256 cols x 2 halves of 8 rows
    const int c = tid & 255;
    const int half = tid >> 8;  // 0..1
    const int r0 = half * 8;
    const float* wr = msgW0 + (c & 127) * 256 + ((c >> 7) << 7);
    float a[8] = {0.f, 0.f, 0.f, 0.f, 0.f, 0.f, 0.f, 0.f};
#pragma unroll 8
    for (int k = 0; k < 128; k += 4) {
      float4 w = *reinterpret_cast<const float4*>(wr + k);
#pragma unroll
      for (int r = 0; r < 8; ++r) {
        const float* x = &hs[r0 + r][k];
        a[r] += w.x * x[0] + w.y * x[1] + w.z * x[2] + w.w * x[3];
      }
    }
    float* dst = (c < 128) ? pj : pi;
    const int oc = c & 127;
#pragma unroll
    for (int r = 0; r < 8; ++r) dst[(m0 + r0 + r) * Hc + oc] = a[r];
  }
}

// ---------------------------------------------------------------------------
// K2/K3: agg(l)+upd(l) [+ pjpi(l+1) | + head]
// agg: sum_j relu(v+s) = 0.5*(sum v + 256*s + sum|v+s|)
// ---------------------------------------------------------------------------
template <bool LAST>
__global__ __launch_bounds__(512) void k_layer(
    const float* __restrict__ pj, const float* __restrict__ pi,
    const float* __restrict__ mb, float* __restrict__ h,
    const float* __restrict__ updWl, const float* __restrict__ updbl,
    const float* __restrict__ msgW2, float* __restrict__ pj2,
    float* __restrict__ pi2, const float* __restrict__ hW1,
    const float* __restrict__ hb1, const float* __restrict__ hW2,
    const float* __restrict__ hb2, float* __restrict__ out) {
  __shared__ float xs[R][Hc];  // h + agg
  __shared__ float hs[R][Hc];  // updated h
  __shared__ float zs[R][Hc];  // head z (LAST only)
  const int m0 = blockIdx.x * R;
  const int b = m0 >> 8;
  const int tid = threadIdx.x;
  const int o = tid & 127;
  const int rg = tid >> 7;  // 0..3 -> rows rg*4 .. rg*4+3
  const int r0 = rg * 4;
  const float* pjb = pj + b * Nc * Hc;

  {  // ---- aggregation: 4 rows per thread ----
    const float mbo = mb[o];
    float s[4], ab[4];
#pragma unroll
    for (int r = 0; r < 4; ++r) {
      s[r] = pi[(m0 + r0 + r) * Hc + o] + mbo;
      ab[r] = 0.f;
    }
    float vsum = 0.f;
#pragma unroll 8
    for (int j = 0; j < Nc; ++j) {
      float v = pjb[j * Hc + o];  // coalesced, L2-hot
      vsum += v;
#pragma unroll
      for (int r = 0; r < 4; ++r) ab[r] += fabsf(v + s[r]);
    }
#pragma unroll
    for (int r = 0; r < 4; ++r) {
      float dj = fmaxf(pj[(m0 + r0 + r) * Hc + o] + s[r], 0.f);
      float sr = 0.5f * (vsum + 256.f * s[r] + ab[r]);
      xs[r0 + r][o] = h[(m0 + r0 + r) * Hc + o] + (sr - dj) * (1.f / 255.f);
    }
  }
  __syncthreads();

  {  // ---- update GEMM: 4 rows per thread ----
    float a[4] = {0.f, 0.f, 0.f, 0.f};
    const float* wr = updWl + o * Hc;
#pragma unroll 8
    for (int k = 0; k < 128; k += 4) {
      float4 w = *reinterpret_cast<const float4*>(wr + k);
#pragma unroll
      for (int r = 0; r < 4; ++r) {
        const float* x = &xs[r0 + r][k];
        a[r] += w.x * x[0] + w.y * x[1] + w.z * x[2] + w.w * x[3];
      }
    }
    const float bo = updbl[o];
#pragma unroll
    for (int r = 0; r < 4; ++r) {
      float v = fmaxf(a[r] + bo, 0.f);
      hs[r0 + r][o] = v;
      if (!LAST) h[(m0 + r0 + r) * Hc + o] = v;
    }
  }
  __syncthreads();

  if (!LAST) {  // ---- pj/pi next layer: 256 cols x 2 halves of 8 rows ----
    const int c = tid & 255;
    const int half = tid >> 8;
    const int rr0 = half * 8;
    const float* wr = msgW2 + (c & 127) * 256 + ((c >> 7) << 7);
    float a[8] = {0.f, 0.f, 0.f, 0.f, 0.f, 0.f, 0.f, 0.f};
#pragma unroll 8
    for (int k = 0; k < 128; k += 4) {
      float4 w = *reinterpret_cast<const float4*>(wr + k);
#pragma unroll
      for (int r = 0; r < 8; ++r) {
        const float* x = &hs[rr0 + r][k];
        a[r] += w.x * x[0] + w.y * x[1] + w.z * x[2] + w.w * x[3];
      }
    }
    float* dst = (c < 128) ? pj2 : pi2;
    const int oc = c & 127;
#pragma unroll
    for (int r = 0; r < 8; ++r) dst[(m0 + rr0 + r) * Hc + oc] = a[r];
  } else {  // ---- head ----
    float a[4] = {0.f, 0.f, 0.f, 0.f};
    const float* wr = hW1 + o * Hc;
#pragma unroll 8
    for (int k = 0; k < 128; k += 4) {
      float4 w = *reinterpret_cast<const float4*>(wr + k);
#pragma unroll
      for (int r = 0; r < 4; ++r) {
        const float* x = &hs[r0 + r][k];
        a[r] += w.x * x[0] + w.y * x[1] + w.z * x[2] + w.w * x[3];
      }
    }
    const float bo = hb1[o];
#pragma unroll
    for (int r = 0; r < 4; ++r) zs[r0 + r][o] = fmaxf(a[r] + bo, 0.f);
    __syncthreads();

    if (tid < R * Ac) {  // 80 dots of length 128
      const int r = tid / Ac;
      const int a2 = tid % Ac;
      const float* wr2 = hW2 + a2 * Hc;
      float sacc = 0.f;
#pragma unroll 8
      for (int k = 0; k < 128; k += 4) {
        float4 w = *reinterpret_cast<const float4*>(wr2 + k);
        sacc += w.x * zs[r][k] + w.y * zs[r][k + 1] + w.z * zs[r][k + 2] +
                w.w * zs[r][k + 3];
      }
      out[(m0 + r) * Ac + a2] = sacc + hb2[a2];
    }
  }
}

// ---------------------------------------------------------------------------
extern "C" void kernel_launch(void* const* d_in, const int* in_sizes, int n_in,
                              void* d_out, int out_size, void* d_ws, size_t ws_size,
                              hipStream_t stream) {
  const float* theta = (const float*)d_in[0];
  const float* cell  = (const float*)d_in[1];
  const float* encW  = (const float*)d_in[2];
  const float* encb  = (const float*)d_in[3];
  const float* msgW  = (const float*)d_in[4];   // (2,128,256)
  const float* msgb  = (const float*)d_in[5];   // (2,128)
  const float* updW  = (const float*)d_in[6];   // (2,128,128)
  const float* updb  = (const float*)d_in[7];   // (2,128)
  const float* hW1   = (const float*)d_in[8];
  const float* hb1   = (const float*)d_in[9];
  const float* hW2   = (const float*)d_in[10];
  const float* hb2   = (const float*)d_in[11];
  float* out = (float*)d_out;

  float* ws = (float*)d_ws;
  const int MH = Mc * Hc;  // 262144
  float* h   = ws;
  float* pjA = ws + MH;
  float* piA = ws + 2 * MH;
  float* pjB = ws + 3 * MH;
  float* piB = ws + 4 * MH;

  k1_enc_pjpi<<<GRID, 512, 0, stream>>>(theta, cell, encW, encb, msgW, h, pjA,
                                        piA);
  k_layer<false><<<GRID, 512, 0, stream>>>(pjA, piA, msgb, h, updW, updb,
                                           msgW + 32768, pjB, piB, hW1, hb1,
                                           hW2, hb2, out);
  k_layer<true><<<GRID, 512, 0, stream>>>(pjB, piB, msgb + Hc, h, updW + 16384,
                                          updb + Hc, nullptr, nullptr, nullptr,
                                          hW1, hb1, hW2, hb2, out);
}

// Round 12
// 61.397 us; speedup vs baseline: 1.8726x; 1.5027x over previous
//
#include <hip/hip_runtime.h>
#include <hip/hip_bf16.h>

// AgentModel: B=8, N=256, TD=128, LH=128, H=128, A=5, L=2
constexpr int Nc = 256;
constexpr int Hc = 128;
constexpr int Ac = 5;
constexpr int Mc = 2048;
constexpr int R = 8;     // rows per block
constexpr int GRID = 256;  // 256 blocks x 256 threads

// Block -> (batch, slice) mapping: b = blk&7 so all 32 blocks of a batch land
// on one XCD (round-robin dispatch) -> batch pj slice stays in that XCD's L2.
__device__ __forceinline__ void rowmap(int blk, int& b, int& sl, int& m0) {
  b = blk & 7;
  sl = blk >> 3;
  m0 = b * 256 + sl * 8;
}

// ---------------------------------------------------------------------------
// K1: encoder + pj/pi of layer 0.
// ---------------------------------------------------------------------------
__global__ __launch_bounds__(256) void k1_enc_pjpi(
    const float* __restrict__ theta, const float* __restrict__ cell,
    const float* __restrict__ encW, const float* __restrict__ encb,
    const float* __restrict__ msgW0, float* __restrict__ h,
    float* __restrict__ pj, float* __restrict__ pi) {
  __shared__ float xs[R][256];
  __shared__ float hs[R][Hc];
  int b, sl, m0;
  rowmap(blockIdx.x, b, sl, m0);
  const int tid = threadIdx.x;

  for (int idx = tid * 4; idx < R * 256; idx += 256 * 4) {
    int r = idx >> 8, d = idx & 255;
    const float* src = (d < 128) ? theta + (m0 + r) * 128 + d
                                 : cell + (m0 + r) * 128 + (d - 128);
    *reinterpret_cast<float4*>(&xs[r][d]) = *reinterpret_cast<const float4*>(src);
  }
  __syncthreads();

  const int o = tid & 127;
  const int rg = tid >> 7;  // 0..1 -> rows rg*4 .. rg*4+3
  {
    float acc[4] = {0, 0, 0, 0};
    const float* wr = encW + o * 256;
#pragma unroll 8
    for (int k = 0; k < 256; k += 4) {
      float4 w = *reinterpret_cast<const float4*>(wr + k);
#pragma unroll
      for (int r = 0; r < 4; ++r) {
        const float* x = &xs[rg * 4 + r][k];
        acc[r] += w.x * x[0] + w.y * x[1] + w.z * x[2] + w.w * x[3];
      }
    }
    const float bb = encb[o];
#pragma unroll
    for (int r = 0; r < 4; ++r) {
      float v = fmaxf(acc[r] + bb, 0.f);
      hs[rg * 4 + r][o] = v;
      h[(m0 + rg * 4 + r) * Hc + o] = v;
    }
  }
  __syncthreads();

  {  // pj/pi layer 0: 256 cols x 8 rows
    const int c = tid;
    const float* wr = msgW0 + (c & 127) * 256 + ((c >> 7) << 7);
    float a[R];
#pragma unroll
    for (int r = 0; r < R; ++r) a[r] = 0.f;
#pragma unroll 8
    for (int k = 0; k < 128; k += 4) {
      float4 w = *reinterpret_cast<const float4*>(wr + k);
#pragma unroll
      for (int r = 0; r < R; ++r) {
        const float* x = &hs[r][k];
        a[r] += w.x * x[0] + w.y * x[1] + w.z * x[2] + w.w * x[3];
      }
    }
    float* dst = (c < 128) ? pj : pi;
    const int oc = c & 127;
#pragma unroll
    for (int r = 0; r < R; ++r) dst[(m0 + r) * Hc + oc] = a[r];
  }
}

// ---------------------------------------------------------------------------
// K2/K3: agg(l)+upd(l) [+ pjpi(l+1) | + head]
// agg: stage batch pj slice into LDS in two 64KB chunks (float4 cooperative
// loads, 16 VMEM instr/thread/chunk), consume via conflict-free ds_read.
// sum_j relu(v+s) = 0.5*(sum v + 256*s + sum|v+s|); diag read from LDS.
// smem reused as xs/hs/zs after agg.
// ---------------------------------------------------------------------------
template <bool LAST>
__global__ __launch_bounds__(256) void k_layer(
    const float* __restrict__ pj, const float* __restrict__ pi,
    const float* __restrict__ mb, float* __restrict__ h,
    const float* __restrict__ updWl, const float* __restrict__ updbl,
    const float* __restrict__ msgW2, float* __restrict__ pj2,
    float* __restrict__ pi2, const float* __restrict__ hW1,
    const float* __restrict__ hb1, const float* __restrict__ hW2,
    const float* __restrict__ hb2, float* __restrict__ out) {
  __shared__ float smem[16384];  // 64 KB stage; later xs/hs/zs
  int b, sl, m0;
  rowmap(blockIdx.x, b, sl, m0);
  const int tid = threadIdx.x;
  const int o = tid & 127;
  const int rg = tid >> 7;  // 0..1 -> rows rg*4 .. rg*4+3
  const float* pjb = pj + b * Nc * Hc;

  // ---- aggregation ----
  const float mbo = mb[o];
  float s[4], ab[4], dj[4];
#pragma unroll
  for (int r = 0; r < 4; ++r) {
    s[r] = pi[(m0 + rg * 4 + r) * Hc + o] + mbo;
    ab[r] = 0.f;
  }
  float vsum = 0.f;
#pragma unroll
  for (int c = 0; c < 2; ++c) {
    {  // stage 128 rows (64 KB): 16 float4 per thread, coalesced
      const float4* src = reinterpret_cast<const float4*>(pjb + c * 16384);
      float4* dst = reinterpret_cast<float4*>(smem);
#pragma unroll
      for (int i = 0; i < 16; ++i) dst[i * 256 + tid] = src[i * 256 + tid];
    }
    __syncthreads();
    if ((sl >> 4) == c) {  // own rows in this chunk: grab diag from LDS
      const int lr = sl * 8 - c * 128;
#pragma unroll
      for (int r = 0; r < 4; ++r) dj[r] = smem[(lr + rg * 4 + r) * 128 + o];
    }
#pragma unroll 8
    for (int j = 0; j < 128; ++j) {
      float v = smem[j * 128 + o];
      vsum += v;
#pragma unroll
      for (int r = 0; r < 4; ++r) ab[r] += fabsf(v + s[r]);
    }
    __syncthreads();  // chunk consumed
  }

  float* xsm = smem;          // [8][128]
  float* hsm = smem + 1024;   // [8][128]
  float* zsm = smem + 2048;   // [8][128] (LAST only)
  {
#pragma unroll
    for (int r = 0; r < 4; ++r) {
      const int row = rg * 4 + r;
      float d = fmaxf(dj[r] + s[r], 0.f);
      float sr = 0.5f * (vsum + 256.f * s[r] + ab[r]);
      xsm[row * 128 + o] =
          h[(m0 + row) * Hc + o] + (sr - d) * (1.f / 255.f);
    }
  }
  __syncthreads();

  {  // ---- update GEMM ----
    float a[4] = {0, 0, 0, 0};
    const float* wr = updWl + o * Hc;
#pragma unroll 8
    for (int k = 0; k < 128; k += 4) {
      float4 w = *reinterpret_cast<const float4*>(wr + k);
#pragma unroll
      for (int r = 0; r < 4; ++r) {
        const float* x = &xsm[(rg * 4 + r) * 128 + k];
        a[r] += w.x * x[0] + w.y * x[1] + w.z * x[2] + w.w * x[3];
      }
    }
    const float bo = updbl[o];
#pragma unroll
    for (int r = 0; r < 4; ++r) {
      float v = fmaxf(a[r] + bo, 0.f);
      hsm[(rg * 4 + r) * 128 + o] = v;
      if (!LAST) h[(m0 + rg * 4 + r) * Hc + o] = v;
    }
  }
  __syncthreads();

  if (!LAST) {  // ---- pj/pi next layer: 256 cols x 8 rows ----
    const int c = tid;
    const float* wr = msgW2 + (c & 127) * 256 + ((c >> 7) << 7);
    float a[R];
#pragma unroll
    for (int r = 0; r < R; ++r) a[r] = 0.f;
#pragma unroll 8
    for (int k = 0; k < 128; k += 4) {
      float4 w = *reinterpret_cast<const float4*>(wr + k);
#pragma unroll
      for (int r = 0; r < R; ++r) {
        const float* x = &hsm[r * 128 + k];
        a[r] += w.x * x[0] + w.y * x[1] + w.z * x[2] + w.w * x[3];
      }
    }
    float* dst = (c < 128) ? pj2 : pi2;
    const int oc = c & 127;
#pragma unroll
    for (int r = 0; r < R; ++r) dst[(m0 + r) * Hc + oc] = a[r];
  } else {  // ---- head ----
    float a[4] = {0, 0, 0, 0};
    const float* wr = hW1 + o * Hc;
#pragma unroll 8
    for (int k = 0; k < 128; k += 4) {
      float4 w = *reinterpret_cast<const float4*>(wr + k);
#pragma unroll
      for (int r = 0; r < 4; ++r) {
        const float* x = &hsm[(rg * 4 + r) * 128 + k];
        a[r] += w.x * x[0] + w.y * x[1] + w.z * x[2] + w.w * x[3];
      }
    }
    const float bo = hb1[o];
#pragma unroll
    for (int r = 0; r < 4; ++r)
      zsm[(rg * 4 + r) * 128 + o] = fmaxf(a[r] + bo, 0.f);
    __syncthreads();

    if (tid < R * Ac) {  // 40 dots of length 128
      const int r = tid / Ac;
      const int a2 = tid % Ac;
      const float* wr2 = hW2 + a2 * Hc;
      float sacc = 0.f;
#pragma unroll 8
      for (int k = 0; k < 128; k += 4) {
        float4 w = *reinterpret_cast<const float4*>(wr2 + k);
        const float* z = &zsm[r * 128 + k];
        sacc += w.x * z[0] + w.y * z[1] + w.z * z[2] + w.w * z[3];
      }
      out[(m0 + r) * Ac + a2] = sacc + hb2[a2];
    }
  }
}

// ---------------------------------------------------------------------------
extern "C" void kernel_launch(void* const* d_in, const int* in_sizes, int n_in,
                              void* d_out, int out_size, void* d_ws, size_t ws_size,
                              hipStream_t stream) {
  const float* theta = (const float*)d_in[0];
  const float* cell  = (const float*)d_in[1];
  const float* encW  = (const float*)d_in[2];
  const float* encb  = (const float*)d_in[3];
  const float* msgW  = (const float*)d_in[4];   // (2,128,256)
  const float* msgb  = (const float*)d_in[5];   // (2,128)
  const float* updW  = (const float*)d_in[6];   // (2,128,128)
  const float* updb  = (const float*)d_in[7];   // (2,128)
  const float* hW1   = (const float*)d_in[8];
  const float* hb1   = (const float*)d_in[9];
  const float* hW2   = (const float*)d_in[10];
  const float* hb2   = (const float*)d_in[11];
  float* out = (float*)d_out;

  float* ws = (float*)d_ws;
  const int MH = Mc * Hc;  // 262144
  float* h   = ws;
  float* pjA = ws + MH;
  float* piA = ws + 2 * MH;
  float* pjB = ws + 3 * MH;
  float* piB = ws + 4 * MH;

  k1_enc_pjpi<<<GRID, 256, 0, stream>>>(theta, cell, encW, encb, msgW, h, pjA,
                                        piA);
  k_layer<false><<<GRID, 256, 0, stream>>>(pjA, piA, msgb, h, updW, updb,
                                           msgW + 32768, pjB, piB, hW1, hb1,
                                           hW2, hb2, out);
  k_layer<true><<<GRID, 256, 0, stream>>>(pjB, piB, msgb + Hc, h, updW + 16384,
                                          updb + Hc, nullptr, nullptr, nullptr,
                                          hW1, hb1, hW2, hb2, out);
}

// Round 13
// 60.758 us; speedup vs baseline: 1.8923x; 1.0105x over previous
//
#include <hip/hip_runtime.h>
#include <hip/hip_bf16.h>

// AgentModel: B=8, N=256, TD=128, LH=128, H=128, A=5, L=2
constexpr int Nc = 256;
constexpr int Hc = 128;
constexpr int Ac = 5;
constexpr int Mc = 2048;
constexpr int R = 8;       // rows per block
constexpr int GRID = 256;  // 256 blocks x 256 threads, 1 block/CU

// Block -> (batch, slice): b = blk&7 so all 32 blocks of a batch land on one
// XCD (round-robin dispatch) -> batch pj slice stays in that XCD's L2.
// (Perf heuristic only; correctness doesn't depend on the mapping.)
__device__ __forceinline__ void rowmap(int blk, int& b, int& sl, int& m0) {
  b = blk & 7;
  sl = blk >> 3;
  m0 = b * 256 + sl * 8;
}

// ---------------------------------------------------------------------------
// K1: encoder + pj/pi of layer 0.  (unchanged from R12)
// ---------------------------------------------------------------------------
__global__ __launch_bounds__(256) void k1_enc_pjpi(
    const float* __restrict__ theta, const float* __restrict__ cell,
    const float* __restrict__ encW, const float* __restrict__ encb,
    const float* __restrict__ msgW0, float* __restrict__ h,
    float* __restrict__ pj, float* __restrict__ pi) {
  __shared__ float xs[R][256];
  __shared__ float hs[R][Hc];
  int b, sl, m0;
  rowmap(blockIdx.x, b, sl, m0);
  const int tid = threadIdx.x;

  for (int idx = tid * 4; idx < R * 256; idx += 256 * 4) {
    int r = idx >> 8, d = idx & 255;
    const float* src = (d < 128) ? theta + (m0 + r) * 128 + d
                                 : cell + (m0 + r) * 128 + (d - 128);
    *reinterpret_cast<float4*>(&xs[r][d]) = *reinterpret_cast<const float4*>(src);
  }
  __syncthreads();

  const int o = tid & 127;
  const int rg = tid >> 7;  // 0..1 -> rows rg*4 .. rg*4+3
  {
    float acc[4] = {0, 0, 0, 0};
    const float* wr = encW + o * 256;
#pragma unroll 8
    for (int k = 0; k < 256; k += 4) {
      float4 w = *reinterpret_cast<const float4*>(wr + k);
#pragma unroll
      for (int r = 0; r < 4; ++r) {
        const float* x = &xs[rg * 4 + r][k];
        acc[r] += w.x * x[0] + w.y * x[1] + w.z * x[2] + w.w * x[3];
      }
    }
    const float bb = encb[o];
#pragma unroll
    for (int r = 0; r < 4; ++r) {
      float v = fmaxf(acc[r] + bb, 0.f);
      hs[rg * 4 + r][o] = v;
      h[(m0 + rg * 4 + r) * Hc + o] = v;
    }
  }
  __syncthreads();

  {  // pj/pi layer 0: 256 cols x 8 rows
    const int c = tid;
    const float* wr = msgW0 + (c & 127) * 256 + ((c >> 7) << 7);
    float a[R];
#pragma unroll
    for (int r = 0; r < R; ++r) a[r] = 0.f;
#pragma unroll 8
    for (int k = 0; k < 128; k += 4) {
      float4 w = *reinterpret_cast<const float4*>(wr + k);
#pragma unroll
      for (int r = 0; r < R; ++r) {
        const float* x = &hs[r][k];
        a[r] += w.x * x[0] + w.y * x[1] + w.z * x[2] + w.w * x[3];
      }
    }
    float* dst = (c < 128) ? pj : pi;
    const int oc = c & 127;
#pragma unroll
    for (int r = 0; r < R; ++r) dst[(m0 + r) * Hc + oc] = a[r];
  }
}

// ---------------------------------------------------------------------------
// K2/K3: agg(l)+upd(l) [+ pjpi(l+1) | + head]
// agg: stage the FULL 128 KB batch pj slice in one shot (32 float4/thread in
// flight); thread = (col-quad q, row r) reads ds_read_b128 per j —
// conflict-free, no cross-thread reduction.
// sum_j relu(v+s) = 0.5*(sum v + 256*s + sum|v+s|); diag from LDS.
// stage buffer reused as xs/hs/zs afterwards.
// ---------------------------------------------------------------------------
template <bool LAST>
__global__ __launch_bounds__(256) void k_layer(
    const float* __restrict__ pj, const float* __restrict__ pi,
    const float* __restrict__ mb, float* __restrict__ h,
    const float* __restrict__ updWl, const float* __restrict__ updbl,
    const float* __restrict__ msgW2, float* __restrict__ pj2,
    float* __restrict__ pi2, const float* __restrict__ hW1,
    const float* __restrict__ hb1, const float* __restrict__ hW2,
    const float* __restrict__ hb2, float* __restrict__ out) {
  __shared__ float smem[Nc * Hc];  // 128 KB: pj slice; later xs/hs/zs
  int b, sl, m0;
  rowmap(blockIdx.x, b, sl, m0);
  const int tid = threadIdx.x;
  const float* pjb = pj + b * Nc * Hc;

  {  // ---- stage whole batch slice: 32 float4/thread, coalesced ----
    const float4* src = reinterpret_cast<const float4*>(pjb);
    float4* dst = reinterpret_cast<float4*>(smem);
#pragma unroll
    for (int i = 0; i < 32; ++i) dst[i * 256 + tid] = src[i * 256 + tid];
  }

  // ---- per-thread setup: thread = (col-quad q, row r) ----
  const int q = tid & 31;   // col-quad: cols 4q..4q+3
  const int r = tid >> 5;   // 0..7
  const int o4 = q * 4;
  float s[4], ab[4], vs[4];
  {
    float4 p4 = *reinterpret_cast<const float4*>(pi + (m0 + r) * Hc + o4);
    float4 m4 = *reinterpret_cast<const float4*>(mb + o4);
    s[0] = p4.x + m4.x; s[1] = p4.y + m4.y;
    s[2] = p4.z + m4.z; s[3] = p4.w + m4.w;
#pragma unroll
    for (int e = 0; e < 4; ++e) { ab[e] = 0.f; vs[e] = 0.f; }
  }
  float4 h4 = *reinterpret_cast<const float4*>(h + (m0 + r) * Hc + o4);

  __syncthreads();  // stage complete

  // ---- j-loop: one ds_read_b128 per j ----
#pragma unroll 8
  for (int j = 0; j < Nc; ++j) {
    float4 v4 = *reinterpret_cast<const float4*>(&smem[j * Hc + o4]);
    float ve[4] = {v4.x, v4.y, v4.z, v4.w};
#pragma unroll
    for (int e = 0; e < 4; ++e) {
      vs[e] += ve[e];
      ab[e] += fabsf(ve[e] + s[e]);
    }
  }
  // diag: own batch-row = sl*8 + r
  float4 d4 = *reinterpret_cast<const float4*>(&smem[(sl * 8 + r) * Hc + o4]);
  float de[4] = {d4.x, d4.y, d4.z, d4.w};
  float he[4] = {h4.x, h4.y, h4.z, h4.w};
  __syncthreads();  // all stage reads done; smem reusable

  float* xsm = smem;         // [8][128]
  float* hsm = smem + 1024;  // [8][128]
  float* zsm = smem + 2048;  // [8][128] (LAST only)
  {
    float xv[4];
#pragma unroll
    for (int e = 0; e < 4; ++e) {
      float dg = fmaxf(de[e] + s[e], 0.f);
      float sr = 0.5f * (vs[e] + 256.f * s[e] + ab[e]);
      xv[e] = he[e] + (sr - dg) * (1.f / 255.f);
    }
    *reinterpret_cast<float4*>(&xsm[r * Hc + o4]) =
        make_float4(xv[0], xv[1], xv[2], xv[3]);
  }
  __syncthreads();

  const int o = tid & 127;
  const int rg = tid >> 7;  // 0..1 -> rows rg*4 .. rg*4+3
  {  // ---- update GEMM ----
    float a[4] = {0, 0, 0, 0};
    const float* wr = updWl + o * Hc;
#pragma unroll 8
    for (int k = 0; k < 128; k += 4) {
      float4 w = *reinterpret_cast<const float4*>(wr + k);
#pragma unroll
      for (int rr = 0; rr < 4; ++rr) {
        const float* x = &xsm[(rg * 4 + rr) * Hc + k];
        a[rr] += w.x * x[0] + w.y * x[1] + w.z * x[2] + w.w * x[3];
      }
    }
    const float bo = updbl[o];
#pragma unroll
    for (int rr = 0; rr < 4; ++rr) {
      float v = fmaxf(a[rr] + bo, 0.f);
      hsm[(rg * 4 + rr) * Hc + o] = v;
      if (!LAST) h[(m0 + rg * 4 + rr) * Hc + o] = v;
    }
  }
  __syncthreads();

  if (!LAST) {  // ---- pj/pi next layer: 256 cols x 8 rows ----
    const int c = tid;
    const float* wr = msgW2 + (c & 127) * 256 + ((c >> 7) << 7);
    float a[R];
#pragma unroll
    for (int rr = 0; rr < R; ++rr) a[rr] = 0.f;
#pragma unroll 8
    for (int k = 0; k < 128; k += 4) {
      float4 w = *reinterpret_cast<const float4*>(wr + k);
#pragma unroll
      for (int rr = 0; rr < R; ++rr) {
        const float* x = &hsm[rr * Hc + k];
        a[rr] += w.x * x[0] + w.y * x[1] + w.z * x[2] + w.w * x[3];
      }
    }
    float* dst = (c < 128) ? pj2 : pi2;
    const int oc = c & 127;
#pragma unroll
    for (int rr = 0; rr < R; ++rr) dst[(m0 + rr) * Hc + oc] = a[rr];
  } else {  // ---- head ----
    float a[4] = {0, 0, 0, 0};
    const float* wr = hW1 + o * Hc;
#pragma unroll 8
    for (int k = 0; k < 128; k += 4) {
      float4 w = *reinterpret_cast<const float4*>(wr + k);
#pragma unroll
      for (int rr = 0; rr < 4; ++rr) {
        const float* x = &hsm[(rg * 4 + rr) * Hc + k];
        a[rr] += w.x * x[0] + w.y * x[1] + w.z * x[2] + w.w * x[3];
      }
    }
    const float bo = hb1[o];
#pragma unroll
    for (int rr = 0; rr < 4; ++rr)
      zsm[(rg * 4 + rr) * Hc + o] = fmaxf(a[rr] + bo, 0.f);
    __syncthreads();

    if (tid < R * Ac) {  // 40 dots of length 128
      const int rr = tid / Ac;
      const int a2 = tid % Ac;
      const float* wr2 = hW2 + a2 * Hc;
      float sacc = 0.f;
#pragma unroll 8
      for (int k = 0; k < 128; k += 4) {
        float4 w = *reinterpret_cast<const float4*>(wr2 + k);
        const float* z = &zsm[rr * Hc + k];
        sacc += w.x * z[0] + w.y * z[1] + w.z * z[2] + w.w * z[3];
      }
      out[(m0 + rr) * Ac + a2] = sacc + hb2[a2];
    }
  }
}

// ---------------------------------------------------------------------------
extern "C" void kernel_launch(void* const* d_in, const int* in_sizes, int n_in,
                              void* d_out, int out_size, void* d_ws, size_t ws_size,
                              hipStream_t stream) {
  const float* theta = (const float*)d_in[0];
  const float* cell  = (const float*)d_in[1];
  const float* encW  = (const float*)d_in[2];
  const float* encb  = (const float*)d_in[3];
  const float* msgW  = (const float*)d_in[4];   // (2,128,256)
  const float* msgb  = (const float*)d_in[5];   // (2,128)
  const float* updW  = (const float*)d_in[6];   // (2,128,128)
  const float* updb  = (const float*)d_in[7];   // (2,128)
  const float* hW1   = (const float*)d_in[8];
  const float* hb1   = (const float*)d_in[9];
  const float* hW2   = (const float*)d_in[10];
  const float* hb2   = (const float*)d_in[11];
  float* out = (float*)d_out;

  float* ws = (float*)d_ws;
  const int MH = Mc * Hc;  // 262144
  float* h   = ws;
  float* pjA = ws + MH;
  float* piA = ws + 2 * MH;
  float* pjB = ws + 3 * MH;
  float* piB = ws + 4 * MH;

  k1_enc_pjpi<<<GRID, 256, 0, stream>>>(theta, cell, encW, encb, msgW, h, pjA,
                                        piA);
  k_layer<false><<<GRID, 256, 0, stream>>>(pjA, piA, msgb, h, updW, updb,
                                           msgW + 32768, pjB, piB, hW1, hb1,
                                           hW2, hb2, out);
  k_layer<true><<<GRID, 256, 0, stream>>>(pjB, piB, msgb + Hc, h, updW + 16384,
                                          updb + Hc, nullptr, nullptr, nullptr,
                                          hW1, hb1, hW2, hb2, out);
}

// Round 14
// 59.531 us; speedup vs baseline: 1.9314x; 1.0206x over previous
//
#include <hip/hip_runtime.h>
#include <hip/hip_bf16.h>

// AgentModel: B=8, N=256, TD=128, LH=128, H=128, A=5, L=2
constexpr int Nc = 256;
constexpr int Hc = 128;
constexpr int Ac = 5;
constexpr int Mc = 2048;
constexpr int R = 8;       // rows per block
constexpr int GRID = 256;  // 256 blocks x 256 threads, 1 block/CU

// Block -> (batch, slice): b = blk&7 so all 32 blocks of a batch land on one
// XCD (round-robin dispatch) -> batch pj slice stays in that XCD's L2.
__device__ __forceinline__ void rowmap(int blk, int& b, int& sl, int& m0) {
  b = blk & 7;
  sl = blk >> 3;
  m0 = b * 256 + sl * 8;
}

// ---------------------------------------------------------------------------
// K1: encoder + pj/pi of layer 0.  (unchanged, proven)
// ---------------------------------------------------------------------------
__global__ __launch_bounds__(256) void k1_enc_pjpi(
    const float* __restrict__ theta, const float* __restrict__ cell,
    const float* __restrict__ encW, const float* __restrict__ encb,
    const float* __restrict__ msgW0, float* __restrict__ h,
    float* __restrict__ pj, float* __restrict__ pi) {
  __shared__ float xs[R][256];
  __shared__ float hs[R][Hc];
  int b, sl, m0;
  rowmap(blockIdx.x, b, sl, m0);
  const int tid = threadIdx.x;

  for (int idx = tid * 4; idx < R * 256; idx += 256 * 4) {
    int r = idx >> 8, d = idx & 255;
    const float* src = (d < 128) ? theta + (m0 + r) * 128 + d
                                 : cell + (m0 + r) * 128 + (d - 128);
    *reinterpret_cast<float4*>(&xs[r][d]) = *reinterpret_cast<const float4*>(src);
  }
  __syncthreads();

  const int o = tid & 127;
  const int rg = tid >> 7;  // 0..1 -> rows rg*4 .. rg*4+3
  {
    float acc[4] = {0, 0, 0, 0};
    const float* wr = encW + o * 256;
#pragma unroll 8
    for (int k = 0; k < 256; k += 4) {
      float4 w = *reinterpret_cast<const float4*>(wr + k);
#pragma unroll
      for (int r = 0; r < 4; ++r) {
        const float* x = &xs[rg * 4 + r][k];
        acc[r] += w.x * x[0] + w.y * x[1] + w.z * x[2] + w.w * x[3];
      }
    }
    const float bb = encb[o];
#pragma unroll
    for (int r = 0; r < 4; ++r) {
      float v = fmaxf(acc[r] + bb, 0.f);
      hs[rg * 4 + r][o] = v;
      h[(m0 + rg * 4 + r) * Hc + o] = v;
    }
  }
  __syncthreads();

  {  // pj/pi layer 0: 256 cols x 8 rows
    const int c = tid;
    const float* wr = msgW0 + (c & 127) * 256 + ((c >> 7) << 7);
    float a[R];
#pragma unroll
    for (int r = 0; r < R; ++r) a[r] = 0.f;
#pragma unroll 8
    for (int k = 0; k < 128; k += 4) {
      float4 w = *reinterpret_cast<const float4*>(wr + k);
#pragma unroll
      for (int r = 0; r < R; ++r) {
        const float* x = &hs[r][k];
        a[r] += w.x * x[0] + w.y * x[1] + w.z * x[2] + w.w * x[3];
      }
    }
    float* dst = (c < 128) ? pj : pi;
    const int oc = c & 127;
#pragma unroll
    for (int r = 0; r < R; ++r) dst[(m0 + r) * Hc + oc] = a[r];
  }
}

// ---------------------------------------------------------------------------
// K2/K3: agg(l)+upd(l) [+ pjpi(l+1) | + head]
// agg: stage the full 128 KB batch pj slice; thread (q=col-quad, r=j-range)
// processes 32 j's for ALL 8 rows (each stage float4 read exactly once:
// 128 b128 wave-instrs vs 1024 before). Partials (ab[8][4], vs[4]) reduced
// across the 8 j-range threads via LDS (written into the dead stage region).
// sum_j relu(v+s) = 0.5*(sum v + 256*s + sum|v+s|); diag from LDS.
// ---------------------------------------------------------------------------
template <bool LAST>
__global__ __launch_bounds__(256) void k_layer(
    const float* __restrict__ pj, const float* __restrict__ pi,
    const float* __restrict__ mb, float* __restrict__ h,
    const float* __restrict__ updWl, const float* __restrict__ updbl,
    const float* __restrict__ msgW2, float* __restrict__ pj2,
    float* __restrict__ pi2, const float* __restrict__ hW1,
    const float* __restrict__ hb1, const float* __restrict__ hW2,
    const float* __restrict__ hb2, float* __restrict__ out) {
  __shared__ float smem[Nc * Hc];  // 128 KB: pj slice; later partials/xs/hs/zs
  int b, sl, m0;
  rowmap(blockIdx.x, b, sl, m0);
  const int tid = threadIdx.x;
  const float* pjb = pj + b * Nc * Hc;

  {  // ---- stage whole batch slice: 32 float4/thread, coalesced ----
    const float4* src = reinterpret_cast<const float4*>(pjb);
    float4* dst = reinterpret_cast<float4*>(smem);
#pragma unroll
    for (int i = 0; i < 32; ++i) dst[i * 256 + tid] = src[i * 256 + tid];
  }

  // ---- per-thread setup: q = col-quad, r = j-range (and own row id) ----
  const int q = tid & 31;
  const int r = tid >> 5;  // 0..7
  const int o4 = q * 4;
  float sA[8][4];  // s for all 8 rows of this col-quad
  {
    float4 m4 = *reinterpret_cast<const float4*>(mb + o4);
#pragma unroll
    for (int row = 0; row < 8; ++row) {
      float4 p4 = *reinterpret_cast<const float4*>(pi + (m0 + row) * Hc + o4);
      sA[row][0] = p4.x + m4.x;
      sA[row][1] = p4.y + m4.y;
      sA[row][2] = p4.z + m4.z;
      sA[row][3] = p4.w + m4.w;
    }
  }
  float4 h4 = *reinterpret_cast<const float4*>(h + (m0 + r) * Hc + o4);

  __syncthreads();  // stage complete

  // ---- j-loop: 32 j's, each float4 read once, all 8 rows accumulated ----
  float vs[4] = {0.f, 0.f, 0.f, 0.f};
  float ab[8][4] = {};
  const int j0 = r * 32;
#pragma unroll 4
  for (int jj = 0; jj < 32; ++jj) {
    float4 v4 = *reinterpret_cast<const float4*>(&smem[(j0 + jj) * Hc + o4]);
    float ve[4] = {v4.x, v4.y, v4.z, v4.w};
#pragma unroll
    for (int e = 0; e < 4; ++e) vs[e] += ve[e];
#pragma unroll
    for (int row = 0; row < 8; ++row)
#pragma unroll
      for (int e = 0; e < 4; ++e) ab[row][e] += fabsf(ve[e] + sA[row][e]);
  }
  // diag for own row r (batch-row sl*8+r), while stage is intact
  float4 d4 = *reinterpret_cast<const float4*>(&smem[(sl * 8 + r) * Hc + o4]);
  float de[4] = {d4.x, d4.y, d4.z, d4.w};
  float he[4] = {h4.x, h4.y, h4.z, h4.w};
  __syncthreads();  // all stage reads done

  // ---- write partials into dead stage region ----
  // AB at float idx row*1024 + r*128 + q*4 ; VS at 8192 + r*128 + q*4
#pragma unroll
  for (int row = 0; row < 8; ++row)
    *reinterpret_cast<float4*>(&smem[row * 1024 + r * 128 + q * 4]) =
        make_float4(ab[row][0], ab[row][1], ab[row][2], ab[row][3]);
  *reinterpret_cast<float4*>(&smem[8192 + r * 128 + q * 4]) =
      make_float4(vs[0], vs[1], vs[2], vs[3]);
  __syncthreads();

  // ---- reduce: thread (q, row=r) sums partials for its (row, col-quad) ----
  float AB[4] = {0.f, 0.f, 0.f, 0.f}, VS[4] = {0.f, 0.f, 0.f, 0.f};
#pragma unroll
  for (int rr = 0; rr < 8; ++rr) {
    float4 a4 = *reinterpret_cast<const float4*>(
        &smem[r * 1024 + rr * 128 + q * 4]);
    float4 v4 = *reinterpret_cast<const float4*>(&smem[8192 + rr * 128 + q * 4]);
    AB[0] += a4.x; AB[1] += a4.y; AB[2] += a4.z; AB[3] += a4.w;
    VS[0] += v4.x; VS[1] += v4.y; VS[2] += v4.z; VS[3] += v4.w;
  }
  float xv[4];
#pragma unroll
  for (int e = 0; e < 4; ++e) {
    float dg = fmaxf(de[e] + sA[r][e], 0.f);
    float sr = 0.5f * (VS[e] + 256.f * sA[r][e] + AB[e]);
    xv[e] = he[e] + (sr - dg) * (1.f / 255.f);
  }
  __syncthreads();  // partial reads done; smem reusable

  float* xsm = smem;         // [8][128]
  float* hsm = smem + 1024;  // [8][128]
  float* zsm = smem + 2048;  // [8][128] (LAST only)
  *reinterpret_cast<float4*>(&xsm[r * Hc + o4]) =
      make_float4(xv[0], xv[1], xv[2], xv[3]);
  __syncthreads();

  const int o = tid & 127;
  const int rg = tid >> 7;  // 0..1 -> rows rg*4 .. rg*4+3
  {  // ---- update GEMM ----
    float a[4] = {0, 0, 0, 0};
    const float* wr = updWl + o * Hc;
#pragma unroll 8
    for (int k = 0; k < 128; k += 4) {
      float4 w = *reinterpret_cast<const float4*>(wr + k);
#pragma unroll
      for (int rr = 0; rr < 4; ++rr) {
        const float* x = &xsm[(rg * 4 + rr) * Hc + k];
        a[rr] += w.x * x[0] + w.y * x[1] + w.z * x[2] + w.w * x[3];
      }
    }
    const float bo = updbl[o];
#pragma unroll
    for (int rr = 0; rr < 4; ++rr) {
      float v = fmaxf(a[rr] + bo, 0.f);
      hsm[(rg * 4 + rr) * Hc + o] = v;
      if (!LAST) h[(m0 + rg * 4 + rr) * Hc + o] = v;
    }
  }
  __syncthreads();

  if (!LAST) {  // ---- pj/pi next layer: 256 cols x 8 rows ----
    const int c = tid;
    const float* wr = msgW2 + (c & 127) * 256 + ((c >> 7) << 7);
    float a[R];
#pragma unroll
    for (int rr = 0; rr < R; ++rr) a[rr] = 0.f;
#pragma unroll 8
    for (int k = 0; k < 128; k += 4) {
      float4 w = *reinterpret_cast<const float4*>(wr + k);
#pragma unroll
      for (int rr = 0; rr < R; ++rr) {
        const float* x = &hsm[rr * Hc + k];
        a[rr] += w.x * x[0] + w.y * x[1] + w.z * x[2] + w.w * x[3];
      }
    }
    float* dst = (c < 128) ? pj2 : pi2;
    const int oc = c & 127;
#pragma unroll
    for (int rr = 0; rr < R; ++rr) dst[(m0 + rr) * Hc + oc] = a[rr];
  } else {  // ---- head ----
    float a[4] = {0, 0, 0, 0};
    const float* wr = hW1 + o * Hc;
#pragma unroll 8
    for (int k = 0; k < 128; k += 4) {
      float4 w = *reinterpret_cast<const float4*>(wr + k);
#pragma unroll
      for (int rr = 0; rr < 4; ++rr) {
        const float* x = &hsm[(rg * 4 + rr) * Hc + k];
        a[rr] += w.x * x[0] + w.y * x[1] + w.z * x[2] + w.w * x[3];
      }
    }
    const float bo = hb1[o];
#pragma unroll
    for (int rr = 0; rr < 4; ++rr)
      zsm[(rg * 4 + rr) * Hc + o] = fmaxf(a[rr] + bo, 0.f);
    __syncthreads();

    if (tid < R * Ac) {  // 40 dots of length 128
      const int rr = tid / Ac;
      const int a2 = tid % Ac;
      const float* wr2 = hW2 + a2 * Hc;
      float sacc = 0.f;
#pragma unroll 8
      for (int k = 0; k < 128; k += 4) {
        float4 w = *reinterpret_cast<const float4*>(wr2 + k);
        const float* z = &zsm[rr * Hc + k];
        sacc += w.x * z[0] + w.y * z[1] + w.z * z[2] + w.w * z[3];
      }
      out[(m0 + rr) * Ac + a2] = sacc + hb2[a2];
    }
  }
}

// ---------------------------------------------------------------------------
extern "C" void kernel_launch(void* const* d_in, const int* in_sizes, int n_in,
                              void* d_out, int out_size, void* d_ws, size_t ws_size,
                              hipStream_t stream) {
  const float* theta = (const float*)d_in[0];
  const float* cell  = (const float*)d_in[1];
  const float* encW  = (const float*)d_in[2];
  const float* encb  = (const float*)d_in[3];
  const float* msgW  = (const float*)d_in[4];   // (2,128,256)
  const float* msgb  = (const float*)d_in[5];   // (2,128)
  const float* updW  = (const float*)d_in[6];   // (2,128,128)
  const float* updb  = (const float*)d_in[7];   // (2,128)
  const float* hW1   = (const float*)d_in[8];
  const float* hb1   = (const float*)d_in[9];
  const float* hW2   = (const float*)d_in[10];
  const float* hb2   = (const float*)d_in[11];
  float* out = (float*)d_out;

  float* ws = (float*)d_ws;
  const int MH = Mc * Hc;  // 262144
  float* h   = ws;
  float* pjA = ws + MH;
  float* piA = ws + 2 * MH;
  float* pjB = ws + 3 * MH;
  float* piB = ws + 4 * MH;

  k1_enc_pjpi<<<GRID, 256, 0, stream>>>(theta, cell, encW, encb, msgW, h, pjA,
                                        piA);
  k_layer<false><<<GRID, 256, 0, stream>>>(pjA, piA, msgb, h, updW, updb,
                                           msgW + 32768, pjB, piB, hW1, hb1,
                                           hW2, hb2, out);
  k_layer<true><<<GRID, 256, 0, stream>>>(pjB, piB, msgb + Hc, h, updW + 16384,
                                          updb + Hc, nullptr, nullptr, nullptr,
                                          hW1, hb1, hW2, hb2, out);
}